// Round 1
// baseline (786.870 us; speedup 1.0000x reference)
//
#include <hip/hip_runtime.h>
#include <stdint.h>
#include <math.h>

// Problem constants (B=4,S=1024 -> T=4096 tokens; D=1024; E=8 experts; F=2816; top-2)
#define T_TOK 4096
#define D_DIM 1024
#define E_EXP 8
#define F_DIM 2816

typedef __attribute__((ext_vector_type(4))) float f32x4;
typedef __attribute__((ext_vector_type(8))) short bf8;          // 8 bf16 = MFMA A/B frag (4 VGPR)
typedef __attribute__((ext_vector_type(4))) float fragc;        // MFMA C/D frag
typedef __attribute__((ext_vector_type(8))) unsigned short u16x8;

__device__ __forceinline__ unsigned short f2bf(float f) {
  union { float f; unsigned u; } v; v.f = f;
  return (unsigned short)((v.u + 0x7fffu + ((v.u >> 16) & 1u)) >> 16);  // RNE
}

__device__ __forceinline__ void pack8(unsigned short* dst, f32x4 a, f32x4 b) {
  u16x8 p;
  p[0] = f2bf(a[0]); p[1] = f2bf(a[1]); p[2] = f2bf(a[2]); p[3] = f2bf(a[3]);
  p[4] = f2bf(b[0]); p[5] = f2bf(b[1]); p[6] = f2bf(b[2]); p[7] = f2bf(b[3]);
  *(u16x8*)dst = p;
}

// async global->LDS, 16B per lane. LDS dest must be wave-uniform base + lane*16.
__device__ __forceinline__ void gload_lds16(const void* g, void* l) {
  __builtin_amdgcn_global_load_lds(
      (__attribute__((address_space(1))) void*)g,
      (__attribute__((address_space(3))) void*)l, 16, 0, 0);
}

// ---------------------------------------------------------------------------
// Router: 1 wave per token. fp64 logits (top-2 pick robustness), top-2 softmax,
// atomic append to per-expert lists. Also converts x row to bf16.
// ---------------------------------------------------------------------------
__global__ __launch_bounds__(256) void router_kernel(
    const float* __restrict__ x, const float* __restrict__ rw,
    unsigned short* __restrict__ xbf, int* __restrict__ counts,
    int* __restrict__ tok_list, float* __restrict__ wgt_list)
{
  const int lane = threadIdx.x & 63;
  const int wv = threadIdx.x >> 6;
  const int t = blockIdx.x * 4 + wv;
  const float* xr = x + (size_t)t * D_DIM;
  float xv[16];
#pragma unroll
  for (int j = 0; j < 16; ++j) xv[j] = xr[lane + j * 64];
  unsigned short* xo = xbf + (size_t)t * D_DIM;
#pragma unroll
  for (int j = 0; j < 16; ++j) xo[lane + j * 64] = f2bf(xv[j]);

  double lg[E_EXP];
#pragma unroll
  for (int e = 0; e < E_EXP; ++e) {
    const float* we = rw + e * D_DIM;
    double s = 0.0;
#pragma unroll
    for (int j = 0; j < 16; ++j) s += (double)xv[j] * (double)we[lane + j * 64];
#pragma unroll
    for (int o = 32; o > 0; o >>= 1) s += __shfl_xor(s, o, 64);
    lg[e] = s;  // all lanes hold the full sum
  }
  int e0 = 0; double v0 = lg[0];
#pragma unroll
  for (int e = 1; e < E_EXP; ++e) if (lg[e] > v0) { v0 = lg[e]; e0 = e; }
  int e1 = -1; double v1 = -1.0e300;
#pragma unroll
  for (int e = 0; e < E_EXP; ++e) if (e != e0 && lg[e] > v1) { v1 = lg[e]; e1 = e; }
  if (lane == 0) {
    float w0 = (float)(1.0 / (1.0 + exp(v1 - v0)));  // softmax over top-2
    float w1 = 1.0f - w0;
    int p0 = atomicAdd(&counts[e0], 1);
    tok_list[e0 * T_TOK + p0] = t;
    wgt_list[e0 * T_TOK + p0] = w0;
    int p1 = atomicAdd(&counts[e1], 1);
    tok_list[e1 * T_TOK + p1] = t;
    wgt_list[e1 * T_TOK + p1] = w1;
  }
}

__global__ void scan_kernel(const int* __restrict__ counts, int* __restrict__ base) {
  if (threadIdx.x == 0) {
    int b = 0;
#pragma unroll
    for (int e = 0; e < E_EXP; ++e) { base[e] = b; b += counts[e]; }
  }
}

// ---------------------------------------------------------------------------
// Phase A: grouped GEMM, gate+up fused (dual accumulators), h = silu(g)*u.
// Tile 128(M tokens) x 64(N over F), BK=64, 256 threads (4 waves, 2Mx2N).
// A = gathered bf16 x rows via global_load_lds; B = fp32 weights reg-staged
// to bf16 LDS. grid (F/64=44, 32 worst-case M-tiles, E=8), early-exit.
// ---------------------------------------------------------------------------
__global__ __launch_bounds__(256) void gemm_gu(
    const unsigned short* __restrict__ xbf,
    const float* __restrict__ wg, const float* __restrict__ wu,
    unsigned short* __restrict__ h,
    const int* __restrict__ counts, const int* __restrict__ base,
    const int* __restrict__ tok_list)
{
  const int e = blockIdx.z;
  const int cnt = counts[e];
  const int m0 = blockIdx.y * 128;
  if (m0 >= cnt) return;
  int mr = cnt - m0; if (mr > 128) mr = 128;
  const int f0 = blockIdx.x * 64;
  const int slotbase = base[e] + m0;
  const int tid = threadIdx.x;
  const int lane = tid & 63;
  const int wv = tid >> 6;

  __shared__ int tokid[128];
  __shared__ unsigned short As[128][64];   // 16 KB
  __shared__ unsigned short Bg[64][64];    // 8 KB
  __shared__ unsigned short Bu[64][64];    // 8 KB

  if (tid < 128) {
    int idx = (tid < mr) ? tid : 0;        // clamp: garbage rows computed, never written
    tokid[tid] = tok_list[e * T_TOK + m0 + idx];
  }
  __syncthreads();

  fragc accg[4][2], accu[4][2];
#pragma unroll
  for (int m = 0; m < 4; ++m)
#pragma unroll
    for (int n = 0; n < 2; ++n) {
      fragc z = {0.f, 0.f, 0.f, 0.f};
      accg[m][n] = z; accu[m][n] = z;
    }

  const float* wge = wg + (size_t)e * F_DIM * D_DIM;
  const float* wue = wu + (size_t)e * F_DIM * D_DIM;
  const int mw = (wv & 1) * 64;
  const int nw = (wv >> 1) * 32;

  for (int k0 = 0; k0 < D_DIM; k0 += 64) {
    // --- stage A (16 KB): 4 x 16B per thread, per-lane gathered source
#pragma unroll
    for (int j = 0; j < 4; ++j) {
      int r = j * 32 + (tid >> 3);
      const unsigned short* src = xbf + (size_t)tokid[r] * D_DIM + k0 + (tid & 7) * 8;
      gload_lds16(src, (char*)(&As[0][0]) + j * 4096 + tid * 16);
    }
    // --- stage Bg/Bu: 16 fp32 each -> bf16 LDS (n = tid>>2, kq = (tid&3)*16)
    {
      int n = tid >> 2;
      int kq = (tid & 3) << 4;
      const f32x4* g4 = (const f32x4*)(wge + (size_t)(f0 + n) * D_DIM + k0 + kq);
      f32x4 a0 = g4[0], a1 = g4[1], a2 = g4[2], a3 = g4[3];
      pack8(&Bg[n][kq], a0, a1);
      pack8(&Bg[n][kq + 8], a2, a3);
      const f32x4* u4 = (const f32x4*)(wue + (size_t)(f0 + n) * D_DIM + k0 + kq);
      f32x4 b0 = u4[0], b1 = u4[1], b2 = u4[2], b3 = u4[3];
      pack8(&Bu[n][kq], b0, b1);
      pack8(&Bu[n][kq + 8], b2, b3);
    }
    __syncthreads();   // drains vmcnt (incl. LDS-DMA) + lgkm before reads
#pragma unroll
    for (int ks = 0; ks < 64; ks += 32) {
      bf8 af[4];
#pragma unroll
      for (int m = 0; m < 4; ++m)
        af[m] = *(const bf8*)&As[mw + m * 16 + (lane & 15)][ks + (lane >> 4) * 8];
      bf8 bg[2], bu[2];
#pragma unroll
      for (int n = 0; n < 2; ++n) {
        bg[n] = *(const bf8*)&Bg[nw + n * 16 + (lane & 15)][ks + (lane >> 4) * 8];
        bu[n] = *(const bf8*)&Bu[nw + n * 16 + (lane & 15)][ks + (lane >> 4) * 8];
      }
#pragma unroll
      for (int m = 0; m < 4; ++m)
#pragma unroll
        for (int n = 0; n < 2; ++n) {
          accg[m][n] = __builtin_amdgcn_mfma_f32_16x16x32_bf16(af[m], bg[n], accg[m][n], 0, 0, 0);
          accu[m][n] = __builtin_amdgcn_mfma_f32_16x16x32_bf16(af[m], bu[n], accu[m][n], 0, 0, 0);
        }
    }
    __syncthreads();   // all reads done before restage
  }

  // epilogue: h = silu(g)*u, bf16. C/D layout: col=lane&15, row=(lane>>4)*4+r
#pragma unroll
  for (int m = 0; m < 4; ++m)
#pragma unroll
    for (int n = 0; n < 2; ++n)
#pragma unroll
      for (int r = 0; r < 4; ++r) {
        int rr = mw + m * 16 + (lane >> 4) * 4 + r;
        if (rr < mr) {
          float g = accg[m][n][r];
          float u = accu[m][n][r];
          float hv = g / (1.f + __expf(-g)) * u;
          int col = f0 + nw + n * 16 + (lane & 15);
          h[(size_t)(slotbase + rr) * F_DIM + col] = f2bf(hv);
        }
      }
}

// ---------------------------------------------------------------------------
// Phase B: grouped GEMM down-proj. Tile 128x128, BK=64, 44 K-steps over F.
// A = h rows (contiguous slots) via global_load_lds; B = fp32 w_down reg-staged.
// Epilogue: *routing_weight, atomicAdd into out. grid (D/128=8, 32, 8).
// ---------------------------------------------------------------------------
__global__ __launch_bounds__(256) void gemm_down(
    const unsigned short* __restrict__ h, const float* __restrict__ wd,
    float* __restrict__ out,
    const int* __restrict__ counts, const int* __restrict__ base,
    const int* __restrict__ tok_list, const float* __restrict__ wgt_list)
{
  const int e = blockIdx.z;
  const int cnt = counts[e];
  const int m0 = blockIdx.y * 128;
  if (m0 >= cnt) return;
  int mr = cnt - m0; if (mr > 128) mr = 128;
  const int d0 = blockIdx.x * 128;
  const int slotbase = base[e] + m0;
  const int tid = threadIdx.x;
  const int lane = tid & 63;
  const int wv = tid >> 6;

  __shared__ int tokid[128];
  __shared__ float tokw[128];
  __shared__ unsigned short As[128][64];   // 16 KB
  __shared__ unsigned short Bs[128][64];   // 16 KB

  if (tid < 128) {
    int idx = (tid < mr) ? tid : 0;
    tokid[tid] = tok_list[e * T_TOK + m0 + idx];
    tokw[tid] = wgt_list[e * T_TOK + m0 + idx];
  }
  __syncthreads();

  fragc acc[4][4];
#pragma unroll
  for (int m = 0; m < 4; ++m)
#pragma unroll
    for (int n = 0; n < 4; ++n) {
      fragc z = {0.f, 0.f, 0.f, 0.f};
      acc[m][n] = z;
    }

  const float* wde = wd + (size_t)e * D_DIM * F_DIM;
  const int mw = (wv & 1) * 64;
  const int nw = (wv >> 1) * 64;

  for (int k0 = 0; k0 < F_DIM; k0 += 64) {
    // --- stage A (16 KB), contiguous slots (clamped at tail)
#pragma unroll
    for (int j = 0; j < 4; ++j) {
      int r = j * 32 + (tid >> 3);
      int rc = (r < mr) ? r : 0;
      const unsigned short* src = h + (size_t)(slotbase + rc) * F_DIM + k0 + (tid & 7) * 8;
      gload_lds16(src, (char*)(&As[0][0]) + j * 4096 + tid * 16);
    }
    // --- stage B: 32 fp32 per thread -> bf16 (n = tid>>1, kq = (tid&1)*32)
    {
      int n = tid >> 1;
      int kq = (tid & 1) * 32;
      const f32x4* b4 = (const f32x4*)(wde + (size_t)(d0 + n) * F_DIM + k0 + kq);
      f32x4 c0 = b4[0], c1 = b4[1], c2 = b4[2], c3 = b4[3];
      pack8(&Bs[n][kq], c0, c1);
      pack8(&Bs[n][kq + 8], c2, c3);
      f32x4 c4 = b4[4], c5 = b4[5], c6 = b4[6], c7 = b4[7];
      pack8(&Bs[n][kq + 16], c4, c5);
      pack8(&Bs[n][kq + 24], c6, c7);
    }
    __syncthreads();
#pragma unroll
    for (int ks = 0; ks < 64; ks += 32) {
      bf8 af[4], bb[4];
#pragma unroll
      for (int m = 0; m < 4; ++m)
        af[m] = *(const bf8*)&As[mw + m * 16 + (lane & 15)][ks + (lane >> 4) * 8];
#pragma unroll
      for (int n = 0; n < 4; ++n)
        bb[n] = *(const bf8*)&Bs[nw + n * 16 + (lane & 15)][ks + (lane >> 4) * 8];
#pragma unroll
      for (int m = 0; m < 4; ++m)
#pragma unroll
        for (int n = 0; n < 4; ++n)
          acc[m][n] = __builtin_amdgcn_mfma_f32_16x16x32_bf16(af[m], bb[n], acc[m][n], 0, 0, 0);
    }
    __syncthreads();
  }

  // epilogue: scale by routing weight, atomic accumulate into out
#pragma unroll
  for (int m = 0; m < 4; ++m)
#pragma unroll
    for (int r = 0; r < 4; ++r) {
      int rr = mw + m * 16 + (lane >> 4) * 4 + r;
      if (rr < mr) {
        int tk = tokid[rr];
        float wf = tokw[rr];
        float* orow = out + (size_t)tk * D_DIM + d0 + nw;
#pragma unroll
        for (int n = 0; n < 4; ++n)
          atomicAdd(orow + n * 16 + (lane & 15), acc[m][n][r] * wf);
      }
    }
}

// ---------------------------------------------------------------------------
extern "C" void kernel_launch(void* const* d_in, const int* in_sizes, int n_in,
                              void* d_out, int out_size, void* d_ws, size_t ws_size,
                              hipStream_t stream) {
  const float* x  = (const float*)d_in[0];   // [T, D]
  const float* rw = (const float*)d_in[1];   // [E, D]
  const float* wg = (const float*)d_in[2];   // [E, F, D]
  const float* wu = (const float*)d_in[3];   // [E, F, D]
  const float* wd = (const float*)d_in[4];   // [E, D, F]
  float* out = (float*)d_out;                // [T, D] fp32

  // workspace layout (~54.6 MB)
  char* ws = (char*)d_ws;
  int* counts = (int*)ws;                                   // 32 B
  int* base = (int*)(ws + 32);                              // 32 B
  int* tok_list = (int*)(ws + 256);                         // E*T*4 = 128 KB
  float* wgt_list = (float*)(ws + 256 + 131072);            // 128 KB
  unsigned short* xbf = (unsigned short*)(ws + 256 + 2 * 131072);          // T*D*2 = 8 MB
  unsigned short* hbuf = (unsigned short*)(ws + 256 + 2 * 131072 + (size_t)T_TOK * D_DIM * 2); // 2T*F*2 = 46 MB

  hipMemsetAsync(counts, 0, 64, stream);
  hipMemsetAsync(out, 0, (size_t)out_size * sizeof(float), stream);

  router_kernel<<<dim3(T_TOK / 4), dim3(256), 0, stream>>>(x, rw, xbf, counts, tok_list, wgt_list);
  scan_kernel<<<dim3(1), dim3(64), 0, stream>>>(counts, base);
  gemm_gu<<<dim3(F_DIM / 64, T_TOK / 128, E_EXP), dim3(256), 0, stream>>>(
      xbf, wg, wu, hbuf, counts, base, tok_list);
  gemm_down<<<dim3(D_DIM / 128, T_TOK / 128, E_EXP), dim3(256), 0, stream>>>(
      hbuf, wd, out, counts, base, tok_list, wgt_list);
}

// Round 2
// 686.562 us; speedup vs baseline: 1.1461x; 1.1461x over previous
//
#include <hip/hip_runtime.h>
#include <stdint.h>
#include <math.h>

// B=4,S=1024 -> T=4096 tokens; D=1024; E=8 experts; F=2816; top-2
#define T_TOK 4096
#define D_DIM 1024
#define E_EXP 8
#define F_DIM 2816

typedef __attribute__((ext_vector_type(4))) float f32x4;
typedef __attribute__((ext_vector_type(8))) short bf8;          // 8 bf16 MFMA frag
typedef __attribute__((ext_vector_type(4))) float fragc;        // MFMA C/D frag
typedef __attribute__((ext_vector_type(8))) unsigned short u16x8;

__device__ __forceinline__ unsigned short f2bf(float f) {
  union { float f; unsigned u; } v; v.f = f;
  return (unsigned short)((v.u + 0x7fffu + ((v.u >> 16) & 1u)) >> 16);  // RNE
}

__device__ __forceinline__ void pack8(unsigned short* dst, f32x4 a, f32x4 b) {
  u16x8 p;
  p[0] = f2bf(a[0]); p[1] = f2bf(a[1]); p[2] = f2bf(a[2]); p[3] = f2bf(a[3]);
  p[4] = f2bf(b[0]); p[5] = f2bf(b[1]); p[6] = f2bf(b[2]); p[7] = f2bf(b[3]);
  *(u16x8*)dst = p;
}

__device__ __forceinline__ void gload_lds16(const void* g, void* l) {
  __builtin_amdgcn_global_load_lds(
      (__attribute__((address_space(1))) void*)g,
      (__attribute__((address_space(3))) void*)l, 16, 0, 0);
}

// ---------------------------------------------------------------------------
// fp32 -> bf16 streaming convert (8 elems/thread/iter, grid-stride)
// ---------------------------------------------------------------------------
__global__ __launch_bounds__(256) void cvt_kernel(
    const float* __restrict__ src, unsigned short* __restrict__ dst, int n8)
{
  int i = blockIdx.x * blockDim.x + threadIdx.x;
  int stride = gridDim.x * blockDim.x;
  for (; i < n8; i += stride) {
    const f32x4* s = (const f32x4*)(src + (size_t)i * 8);
    f32x4 a = s[0], b = s[1];
    pack8(dst + (size_t)i * 8, a, b);
  }
}

// ---------------------------------------------------------------------------
// Router: 1 wave/token, fp64 logits, top-2 softmax, atomic expert lists,
// x -> bf16.
// ---------------------------------------------------------------------------
__global__ __launch_bounds__(256) void router_kernel(
    const float* __restrict__ x, const float* __restrict__ rw,
    unsigned short* __restrict__ xbf, int* __restrict__ counts,
    int* __restrict__ tok_list, float* __restrict__ wgt_list)
{
  const int lane = threadIdx.x & 63;
  const int wv = threadIdx.x >> 6;
  const int t = blockIdx.x * 4 + wv;
  const float* xr = x + (size_t)t * D_DIM;
  float xv[16];
#pragma unroll
  for (int j = 0; j < 16; ++j) xv[j] = xr[lane + j * 64];
  unsigned short* xo = xbf + (size_t)t * D_DIM;
#pragma unroll
  for (int j = 0; j < 16; ++j) xo[lane + j * 64] = f2bf(xv[j]);

  double lg[E_EXP];
#pragma unroll
  for (int e = 0; e < E_EXP; ++e) {
    const float* we = rw + e * D_DIM;
    double s = 0.0;
#pragma unroll
    for (int j = 0; j < 16; ++j) s += (double)xv[j] * (double)we[lane + j * 64];
#pragma unroll
    for (int o = 32; o > 0; o >>= 1) s += __shfl_xor(s, o, 64);
    lg[e] = s;
  }
  int e0 = 0; double v0 = lg[0];
#pragma unroll
  for (int e = 1; e < E_EXP; ++e) if (lg[e] > v0) { v0 = lg[e]; e0 = e; }
  int e1 = -1; double v1 = -1.0e300;
#pragma unroll
  for (int e = 0; e < E_EXP; ++e) if (e != e0 && lg[e] > v1) { v1 = lg[e]; e1 = e; }
  if (lane == 0) {
    float w0 = (float)(1.0 / (1.0 + exp(v1 - v0)));
    float w1 = 1.0f - w0;
    int p0 = atomicAdd(&counts[e0], 1);
    tok_list[e0 * T_TOK + p0] = t;
    wgt_list[e0 * T_TOK + p0] = w0;
    int p1 = atomicAdd(&counts[e1], 1);
    tok_list[e1 * T_TOK + p1] = t;
    wgt_list[e1 * T_TOK + p1] = w1;
  }
}

__global__ void scan_kernel(const int* __restrict__ counts, int* __restrict__ base) {
  if (threadIdx.x == 0) {
    int b = 0;
#pragma unroll
    for (int e = 0; e < E_EXP; ++e) { base[e] = b; b += counts[e]; }
  }
}

// ---------------------------------------------------------------------------
// Phase A: grouped GEMM, gate+up fused. BM=128, BN=64 (per matrix), BK=64.
// 4 waves (2M x 2N): wave tile 64x32 for each of gate/up. All operands via
// global_load_lds (bf16). h = silu(g)*u.
// ---------------------------------------------------------------------------
__global__ __launch_bounds__(256) void gemm_gu(
    const unsigned short* __restrict__ xbf,
    const unsigned short* __restrict__ wgb, const unsigned short* __restrict__ wub,
    unsigned short* __restrict__ h,
    const int* __restrict__ counts, const int* __restrict__ base,
    const int* __restrict__ tok_list)
{
  const int e = blockIdx.z;
  const int cnt = counts[e];
  const int m0 = blockIdx.y * 128;
  if (m0 >= cnt) return;
  int mr = cnt - m0; if (mr > 128) mr = 128;
  const int f0 = blockIdx.x * 64;
  const int slotbase = base[e] + m0;
  const int tid = threadIdx.x;
  const int lane = tid & 63;
  const int wv = tid >> 6;
  const int mw = (wv >> 1) * 64;
  const int nw = (wv & 1) * 32;

  __shared__ int tokid[128];
  __shared__ unsigned short As[128][64];   // 16 KB
  __shared__ unsigned short Bg[64][64];    // 8 KB
  __shared__ unsigned short Bu[64][64];    // 8 KB

  if (tid < 128) {
    int idx = (tid < mr) ? tid : 0;
    tokid[tid] = tok_list[e * T_TOK + m0 + idx];
  }
  __syncthreads();

  fragc accg[4][2], accu[4][2];
#pragma unroll
  for (int m = 0; m < 4; ++m)
#pragma unroll
    for (int n = 0; n < 2; ++n) {
      fragc z = {0.f, 0.f, 0.f, 0.f};
      accg[m][n] = z; accu[m][n] = z;
    }

  const unsigned short* wge = wgb + (size_t)e * F_DIM * D_DIM;
  const unsigned short* wue = wub + (size_t)e * F_DIM * D_DIM;
  const int cchunk = (tid & 7) * 8;   // k-offset of this thread's 16B chunk
  const int rhalf = tid >> 3;         // 0..31

  for (int k0 = 0; k0 < D_DIM; k0 += 64) {
    // A: 128x64 bf16 = 4 x 16B/thread, gathered rows
#pragma unroll
    for (int j = 0; j < 4; ++j) {
      int r = j * 32 + rhalf;
      gload_lds16(xbf + (size_t)tokid[r] * D_DIM + k0 + cchunk,
                  (char*)(&As[0][0]) + (j * 256 + tid) * 16);
    }
    // Bg/Bu: 64x64 bf16 = 2 x 16B/thread each
#pragma unroll
    for (int j = 0; j < 2; ++j) {
      int r = j * 32 + rhalf;
      gload_lds16(wge + (size_t)(f0 + r) * D_DIM + k0 + cchunk,
                  (char*)(&Bg[0][0]) + (j * 256 + tid) * 16);
      gload_lds16(wue + (size_t)(f0 + r) * D_DIM + k0 + cchunk,
                  (char*)(&Bu[0][0]) + (j * 256 + tid) * 16);
    }
    __syncthreads();
#pragma unroll
    for (int ks = 0; ks < 64; ks += 32) {
      bf8 af[4];
#pragma unroll
      for (int m = 0; m < 4; ++m)
        af[m] = *(const bf8*)&As[mw + m * 16 + (lane & 15)][ks + (lane >> 4) * 8];
      bf8 bg[2], bu[2];
#pragma unroll
      for (int n = 0; n < 2; ++n) {
        bg[n] = *(const bf8*)&Bg[nw + n * 16 + (lane & 15)][ks + (lane >> 4) * 8];
        bu[n] = *(const bf8*)&Bu[nw + n * 16 + (lane & 15)][ks + (lane >> 4) * 8];
      }
#pragma unroll
      for (int m = 0; m < 4; ++m)
#pragma unroll
        for (int n = 0; n < 2; ++n) {
          accg[m][n] = __builtin_amdgcn_mfma_f32_16x16x32_bf16(af[m], bg[n], accg[m][n], 0, 0, 0);
          accu[m][n] = __builtin_amdgcn_mfma_f32_16x16x32_bf16(af[m], bu[n], accu[m][n], 0, 0, 0);
        }
    }
    __syncthreads();
  }

  // epilogue: h = silu(g)*u (bf16). C/D: col=lane&15, row=(lane>>4)*4+r
#pragma unroll
  for (int m = 0; m < 4; ++m)
#pragma unroll
    for (int n = 0; n < 2; ++n)
#pragma unroll
      for (int r = 0; r < 4; ++r) {
        int rr = mw + m * 16 + (lane >> 4) * 4 + r;
        if (rr < mr) {
          float g = accg[m][n][r];
          float u = accu[m][n][r];
          float hv = g / (1.f + __expf(-g)) * u;
          int col = f0 + nw + n * 16 + (lane & 15);
          h[(size_t)(slotbase + rr) * F_DIM + col] = f2bf(hv);
        }
      }
}

// ---------------------------------------------------------------------------
// Phase B: grouped down-proj GEMM. BM=64, BN=128, BK=64 (44 K-steps).
// 4 waves (2M x 2N): wave tile 32x64. Both operands via global_load_lds.
// Epilogue: * routing weight, atomicAdd into out.
// ---------------------------------------------------------------------------
__global__ __launch_bounds__(256) void gemm_down(
    const unsigned short* __restrict__ h, const unsigned short* __restrict__ wdb,
    float* __restrict__ out,
    const int* __restrict__ counts, const int* __restrict__ base,
    const int* __restrict__ tok_list, const float* __restrict__ wgt_list)
{
  const int e = blockIdx.z;
  const int cnt = counts[e];
  const int m0 = blockIdx.y * 64;
  if (m0 >= cnt) return;
  int mr = cnt - m0; if (mr > 64) mr = 64;
  const int d0 = blockIdx.x * 128;
  const int slotbase = base[e] + m0;
  const int tid = threadIdx.x;
  const int lane = tid & 63;
  const int wv = tid >> 6;
  const int mw = (wv >> 1) * 32;
  const int nw = (wv & 1) * 64;

  __shared__ int tokid[64];
  __shared__ float tokw[64];
  __shared__ unsigned short As[64][64];    // 8 KB
  __shared__ unsigned short Bs[128][64];   // 16 KB

  if (tid < 64) {
    int idx = (tid < mr) ? tid : 0;
    tokid[tid] = tok_list[e * T_TOK + m0 + idx];
    tokw[tid] = wgt_list[e * T_TOK + m0 + idx];
  }
  __syncthreads();

  fragc acc[2][4];
#pragma unroll
  for (int m = 0; m < 2; ++m)
#pragma unroll
    for (int n = 0; n < 4; ++n) {
      fragc z = {0.f, 0.f, 0.f, 0.f};
      acc[m][n] = z;
    }

  const unsigned short* wde = wdb + (size_t)e * D_DIM * F_DIM;
  const int cchunk = (tid & 7) * 8;
  const int rhalf = tid >> 3;   // 0..31

  for (int k0 = 0; k0 < F_DIM; k0 += 64) {
    // A: 64x64 = 2 x 16B/thread, contiguous slots (clamped at tail)
#pragma unroll
    for (int j = 0; j < 2; ++j) {
      int r = j * 32 + rhalf;
      int rc = (r < mr) ? r : 0;
      gload_lds16(h + (size_t)(slotbase + rc) * F_DIM + k0 + cchunk,
                  (char*)(&As[0][0]) + (j * 256 + tid) * 16);
    }
    // B: 128x64 = 4 x 16B/thread
#pragma unroll
    for (int j = 0; j < 4; ++j) {
      int r = j * 32 + rhalf;
      gload_lds16(wde + (size_t)(d0 + r) * F_DIM + k0 + cchunk,
                  (char*)(&Bs[0][0]) + (j * 256 + tid) * 16);
    }
    __syncthreads();
#pragma unroll
    for (int ks = 0; ks < 64; ks += 32) {
      bf8 af[2], bb[4];
#pragma unroll
      for (int m = 0; m < 2; ++m)
        af[m] = *(const bf8*)&As[mw + m * 16 + (lane & 15)][ks + (lane >> 4) * 8];
#pragma unroll
      for (int n = 0; n < 4; ++n)
        bb[n] = *(const bf8*)&Bs[nw + n * 16 + (lane & 15)][ks + (lane >> 4) * 8];
#pragma unroll
      for (int m = 0; m < 2; ++m)
#pragma unroll
        for (int n = 0; n < 4; ++n)
          acc[m][n] = __builtin_amdgcn_mfma_f32_16x16x32_bf16(af[m], bb[n], acc[m][n], 0, 0, 0);
    }
    __syncthreads();
  }

#pragma unroll
  for (int m = 0; m < 2; ++m)
#pragma unroll
    for (int r = 0; r < 4; ++r) {
      int rr = mw + m * 16 + (lane >> 4) * 4 + r;
      if (rr < mr) {
        int tk = tokid[rr];
        float wf = tokw[rr];
        float* orow = out + (size_t)tk * D_DIM + d0 + nw;
#pragma unroll
        for (int n = 0; n < 4; ++n)
          atomicAdd(orow + n * 16 + (lane & 15), acc[m][n][r] * wf);
      }
    }
}

// ---------------------------------------------------------------------------
extern "C" void kernel_launch(void* const* d_in, const int* in_sizes, int n_in,
                              void* d_out, int out_size, void* d_ws, size_t ws_size,
                              hipStream_t stream) {
  const float* x  = (const float*)d_in[0];   // [T, D]
  const float* rw = (const float*)d_in[1];   // [E, D]
  const float* wg = (const float*)d_in[2];   // [E, F, D]
  const float* wu = (const float*)d_in[3];   // [E, F, D]
  const float* wd = (const float*)d_in[4];   // [E, D, F]
  float* out = (float*)d_out;                // [T, D] fp32

  // workspace layout (~147 MB peak):
  //   counts 32B @0 | base @64 | tok_list 128KB @256 | wgt_list 128KB
  //   xbf 8MB | hbuf 46.2MB | wbf0 46.2MB (wg_bf, later wd_bf) | wbf1 46.2MB (wu_bf)
  char* ws = (char*)d_ws;
  int* counts = (int*)ws;
  int* base = (int*)(ws + 64);
  int* tok_list = (int*)(ws + 256);
  float* wgt_list = (float*)(ws + 256 + 131072);
  unsigned short* xbf  = (unsigned short*)(ws + 262400);
  unsigned short* hbuf = (unsigned short*)(ws + 8651008);
  unsigned short* wbf0 = (unsigned short*)(ws + 54788352);
  unsigned short* wbf1 = (unsigned short*)(ws + 100925696);

  const int W_N8 = E_EXP * F_DIM * D_DIM / 8;  // 2883584

  hipMemsetAsync(counts, 0, 64, stream);
  hipMemsetAsync(out, 0, (size_t)out_size * sizeof(float), stream);

  router_kernel<<<dim3(T_TOK / 4), dim3(256), 0, stream>>>(x, rw, xbf, counts, tok_list, wgt_list);
  scan_kernel<<<dim3(1), dim3(64), 0, stream>>>(counts, base);
  cvt_kernel<<<dim3(2048), dim3(256), 0, stream>>>(wg, wbf0, W_N8);
  cvt_kernel<<<dim3(2048), dim3(256), 0, stream>>>(wu, wbf1, W_N8);
  gemm_gu<<<dim3(F_DIM / 64, T_TOK / 128, E_EXP), dim3(256), 0, stream>>>(
      xbf, wbf0, wbf1, hbuf, counts, base, tok_list);
  cvt_kernel<<<dim3(2048), dim3(256), 0, stream>>>(wd, wbf0, W_N8);   // reuse wbf0
  gemm_down<<<dim3(D_DIM / 128, T_TOK / 64, E_EXP), dim3(256), 0, stream>>>(
      hbuf, wbf0, out, counts, base, tok_list, wgt_list);
}